// Round 7
// baseline (177.338 us; speedup 1.0000x reference)
//
#include <hip/hip_runtime.h>
#include <hip/hip_bf16.h>

typedef __attribute__((ext_vector_type(4))) float f32x4;
typedef __attribute__((ext_vector_type(8))) short bf16x8;

constexpr int Bn  = 4;
constexpr int Ln  = 1024;
constexpr int Dn  = 1024;
constexpr int Hn  = 16;
constexpr int HDn = 64;

static __device__ __forceinline__ unsigned short bf16r(float f) {
    union { float f; unsigned int u; } x;
    x.f = f;
    unsigned int r = x.u + 0x7fffu + ((x.u >> 16) & 1u);
    return (unsigned short)(r >> 16);
}

static __device__ __forceinline__ unsigned int pk2(float a, float b) {
    return (unsigned int)bf16r(a) | ((unsigned int)bf16r(b) << 16);
}

// ---------------------------------------------------------------------------
// Fused prep. grid (16,16,5) x 256 threads.  (unchanged)
// ---------------------------------------------------------------------------
__global__ __launch_bounds__(256) void prep_kernel(
    const float* __restrict__ Kg, const float* __restrict__ Vg,
    const float* __restrict__ Wg, unsigned short* __restrict__ Kbf,
    unsigned short* __restrict__ Vtg, unsigned short* __restrict__ Wbf)
{
    const int tid = threadIdx.x;
    if (blockIdx.z == 4) {
        const int r0 = blockIdx.x * 64, c0 = blockIdx.y * 64;
#pragma unroll 4
        for (int i = 0; i < 4; ++i) {
            int e4 = i * 256 + tid;
            int r = e4 >> 4, c4 = e4 & 15;
            const float* p = Wg + (size_t)(r0 + r) * Dn + c0 + c4 * 4;
            float4 v = *(const float4*)p;
            ushort4 o;
            o.x = bf16r(v.x); o.y = bf16r(v.y); o.z = bf16r(v.z); o.w = bf16r(v.w);
            *(ushort4*)(Wbf + (size_t)(r0 + r) * Dn + c0 + c4 * 4) = o;
        }
        return;
    }

    __shared__ unsigned short T[64][72];   // [d][k]
    const int k0 = blockIdx.x * 64;
    const int h  = blockIdx.y;
    const int b  = blockIdx.z;
    const float* Kb = Kg + (size_t)b * Ln * Dn + h * HDn;
    const float* Vb = Vg + (size_t)b * Ln * Dn + h * HDn;
    unsigned short* Ko = Kbf + (size_t)b * Ln * Dn + h * HDn;

#pragma unroll 4
    for (int i = 0; i < 4; ++i) {
        int e4 = i * 256 + tid;
        int r = e4 >> 4, c4 = e4 & 15;
        float4 kv = *(const float4*)(Kb + (size_t)(k0 + r) * Dn + c4 * 4);
        ushort4 o;
        o.x = bf16r(kv.x); o.y = bf16r(kv.y); o.z = bf16r(kv.z); o.w = bf16r(kv.w);
        *(ushort4*)(Ko + (size_t)(k0 + r) * Dn + c4 * 4) = o;
        float4 vv = *(const float4*)(Vb + (size_t)(k0 + r) * Dn + c4 * 4);
        T[c4 * 4 + 0][r] = bf16r(vv.x);
        T[c4 * 4 + 1][r] = bf16r(vv.y);
        T[c4 * 4 + 2][r] = bf16r(vv.z);
        T[c4 * 4 + 3][r] = bf16r(vv.w);
    }
    __syncthreads();
    unsigned short* out = Vtg + ((size_t)(b * Hn + h) * HDn) * Ln + k0;
#pragma unroll 2
    for (int i = 0; i < 2; ++i) {
        int e8 = i * 256 + tid;
        int r = e8 >> 3, c8 = e8 & 7;
        *(uint4*)(out + (size_t)r * Ln + c8 * 8) = *(const uint4*)&T[r][c8 * 8];
    }
}

// ---------------------------------------------------------------------------
// Flash attention, v6: same per-wave shape as the 33us v2 (32 q-rows/wave,
// swapped QK^T, packed b64 P-stores, reg prefetch, builtin exp2, forced
// unrolls) but 256 threads / 4 waves / q-tile 128, grid 512 = 2 blocks/CU.
// Round-1 profile showed v2 latency-bound (MfmaUtil 19%, VALU 23%, HBM 31%,
// 1 block/CU lockstep): two independent barrier domains per CU let one
// block's staging overlap the other's MFMA/exp. LDS 36.9 KB -> 2 fit.
// XCD decode: all 8 q-tiles of one (b,h) on one XCD (K/V 2MB < L2).
// ---------------------------------------------------------------------------
__global__ __launch_bounds__(256) void attn_kernel(
    const float* __restrict__ Qg, const unsigned short* __restrict__ Kbf,
    const unsigned short* __restrict__ Vtg, unsigned short* __restrict__ Xg)
{
    __shared__ uint4 Ks4[64][9];     // 64 rows x 72 shorts (8 pad shorts)
    __shared__ uint4 Vts4[64][9];    // [d][k], same padding
    __shared__ uint2 Ps2[128][18];   // 128 rows x 72 shorts

    const int tid  = threadIdx.x;
    const int wave = tid >> 6;     // 0..3
    const int lane = tid & 63;
    const int l16  = lane & 15;
    const int quad = lane >> 4;
    const int wb   = wave * 32;    // wave's q-row base within the 128-row tile

    // XCD-aware decode: flat = xcd + 8*(qt + 8*gg); (b,h) = xcd + 8*gg.
    const int flat = blockIdx.x;
    const int xcd  = flat & 7;
    const int j    = flat >> 3;    // 0..63
    const int qt   = j & 7;
    const int gg   = j >> 3;
    const int g    = xcd + 8 * gg; // 0..63
    const int h    = g & 15;
    const int b    = g >> 4;
    const int q0   = qt * 128;

    const uint4* Kb4  = (const uint4*)(Kbf + (size_t)b * Ln * Dn + h * HDn);
    const uint4* Vtb4 = (const uint4*)(Vtg + ((size_t)(b * Hn + h) * HDn) * Ln);

    // Q fragments (read exactly once). B-operand layout: n=l16, k=quad*8+j.
    bf16x8 bq[2][2];
#pragma unroll 2
    for (int hf = 0; hf < 2; ++hf) {
        const float* qp = Qg + ((size_t)b * Ln + q0 + wb + hf * 16 + l16) * Dn
                             + h * HDn + quad * 8;
        float4 a0 = *(const float4*)qp;
        float4 a1 = *(const float4*)(qp + 4);
        float4 a2 = *(const float4*)(qp + 32);
        float4 a3 = *(const float4*)(qp + 36);
        bq[hf][0][0] = (short)bf16r(a0.x); bq[hf][0][1] = (short)bf16r(a0.y);
        bq[hf][0][2] = (short)bf16r(a0.z); bq[hf][0][3] = (short)bf16r(a0.w);
        bq[hf][0][4] = (short)bf16r(a1.x); bq[hf][0][5] = (short)bf16r(a1.y);
        bq[hf][0][6] = (short)bf16r(a1.z); bq[hf][0][7] = (short)bf16r(a1.w);
        bq[hf][1][0] = (short)bf16r(a2.x); bq[hf][1][1] = (short)bf16r(a2.y);
        bq[hf][1][2] = (short)bf16r(a2.z); bq[hf][1][3] = (short)bf16r(a2.w);
        bq[hf][1][4] = (short)bf16r(a3.x); bq[hf][1][5] = (short)bf16r(a3.y);
        bq[hf][1][6] = (short)bf16r(a3.z); bq[hf][1][7] = (short)bf16r(a3.w);
    }

    const float SC = 1.4426950408889634f / 32.0f;   // log2(e)/sqrt(D)

    float lsum[2] = {0.f, 0.f};
    f32x4 Oacc[2][4];
#pragma unroll 2
    for (int hf = 0; hf < 2; ++hf)
#pragma unroll 4
        for (int d = 0; d < 4; ++d) Oacc[hf][d] = (f32x4){0.f, 0.f, 0.f, 0.f};

    // Stage addressing: 256 threads, two uint4 per array per tile.
    uint4 kreg[2], vreg[2];
#pragma unroll 2
    for (int i = 0; i < 2; ++i) {
        int idx = i * 256 + tid, r = idx >> 3, c = idx & 7;
        kreg[i] = Kb4[(size_t)r * 128 + c];
        vreg[i] = Vtb4[(size_t)r * 128 + c];
    }

    for (int it = 0; it < Ln / 64; ++it) {
        __syncthreads();   // previous tile's compute done -> Ks/Vts free
#pragma unroll 2
        for (int i = 0; i < 2; ++i) {
            int idx = i * 256 + tid, r = idx >> 3, c = idx & 7;
            Ks4[r][c]  = kreg[i];
            Vts4[r][c] = vreg[i];
        }
        if (it + 1 < Ln / 64) {   // prefetch next tile; hides under compute
#pragma unroll 2
            for (int i = 0; i < 2; ++i) {
                int idx = i * 256 + tid, r = idx >> 3, c = idx & 7;
                kreg[i] = Kb4[(size_t)(((it + 1) * 64) + r) * 128 + c];
                vreg[i] = Vtb4[(size_t)r * 128 + (it + 1) * 8 + c];
            }
        }
        __syncthreads();

        // S^T = K Q^T : A = K-frag (m=key), B = Q-frag (n=q). 8 reads, 16 MFMA.
        f32x4 st[2][4];
        __builtin_amdgcn_s_setprio(1);
#pragma unroll 4
        for (int n = 0; n < 4; ++n) {
            bf16x8 a0 = *(const bf16x8*)&Ks4[n * 16 + l16][quad];
            bf16x8 a1 = *(const bf16x8*)&Ks4[n * 16 + l16][4 + quad];
#pragma unroll 2
            for (int hf = 0; hf < 2; ++hf) {
                f32x4 acc = (f32x4){0.f, 0.f, 0.f, 0.f};
                acc = __builtin_amdgcn_mfma_f32_16x16x32_bf16(a0, bq[hf][0], acc, 0, 0, 0);
                acc = __builtin_amdgcn_mfma_f32_16x16x32_bf16(a1, bq[hf][1], acc, 0, 0, 0);
                st[hf][n] = acc;
            }
        }
        __builtin_amdgcn_s_setprio(0);

        // P = exp2(S^T * SC). Lane holds keys 16n+quad*4+(0..3) for q=l16:
        // k-consecutive -> pack pairs, one b64 store per n. Scalar row-sum.
#pragma unroll 2
        for (int hf = 0; hf < 2; ++hf) {
            float ls = 0.f;
#pragma unroll 4
            for (int n = 0; n < 4; ++n) {
                float p0 = __builtin_amdgcn_exp2f(st[hf][n][0] * SC);
                float p1 = __builtin_amdgcn_exp2f(st[hf][n][1] * SC);
                float p2 = __builtin_amdgcn_exp2f(st[hf][n][2] * SC);
                float p3 = __builtin_amdgcn_exp2f(st[hf][n][3] * SC);
                ls += (p0 + p1) + (p2 + p3);
                uint2 w;
                w.x = pk2(p0, p1);
                w.y = pk2(p2, p3);
                Ps2[wb + hf * 16 + l16][n * 4 + quad] = w;
            }
            lsum[hf] += ls;
        }

        // O += P V. V B-frags shared across the two q-halves.
        __builtin_amdgcn_s_setprio(1);
#pragma unroll 2
        for (int kk = 0; kk < 2; ++kk) {
            bf16x8 bv[4];
#pragma unroll 4
            for (int dt = 0; dt < 4; ++dt)
                bv[dt] = *(const bf16x8*)&Vts4[dt * 16 + l16][kk * 4 + quad];
#pragma unroll 2
            for (int hf = 0; hf < 2; ++hf) {
                bf16x8 ap = *(const bf16x8*)&Ps2[wb + hf * 16 + l16][kk * 8 + quad * 2];
#pragma unroll 4
                for (int dt = 0; dt < 4; ++dt)
                    Oacc[hf][dt] = __builtin_amdgcn_mfma_f32_16x16x32_bf16(
                        ap, bv[dt], Oacc[hf][dt], 0, 0, 0);
            }
        }
        __builtin_amdgcn_s_setprio(0);
    }

    // Row sums live per-lane (q=l16); reduce across quads.
    float inv[2];
#pragma unroll 2
    for (int hf = 0; hf < 2; ++hf) {
        float rs = lsum[hf];
        rs += __shfl_xor(rs, 16, 64);
        rs += __shfl_xor(rs, 32, 64);
        inv[hf] = __builtin_amdgcn_rcpf(rs);
    }

    unsigned short* Xb = Xg + ((size_t)b * Ln + q0 + wb) * Dn + h * HDn;
#pragma unroll 2
    for (int hf = 0; hf < 2; ++hf)
#pragma unroll 4
        for (int r = 0; r < 4; ++r) {
            float iv = __shfl(inv[hf], quad * 4 + r, 64);
            int row = hf * 16 + quad * 4 + r;
#pragma unroll 4
            for (int dt = 0; dt < 4; ++dt)
                Xb[(size_t)row * Dn + dt * 16 + l16] = bf16r(Oacc[hf][dt][r] * iv);
        }
}

// ---------------------------------------------------------------------------
// Projection: Y = X @ W^T + b.  (unchanged from round 6)
// ---------------------------------------------------------------------------
__global__ __launch_bounds__(256) void proj_kernel(
    const unsigned short* __restrict__ Xg, const unsigned short* __restrict__ Wbf,
    const float* __restrict__ bg, float* __restrict__ Yg)
{
    __shared__ unsigned short XsL[128 * 64];   // 16 KB, linear (no pad!)
    __shared__ unsigned short WsL[64 * 64];    // 8 KB, linear

    const int tid  = threadIdx.x;
    const int wave = tid >> 6;
    const int lane = tid & 63;
    const int l16  = lane & 15;
    const int quad = lane >> 4;
    const int mw   = (wave & 1) * 64;
    const int nw   = (wave >> 1) * 32;

    const int m0 = blockIdx.x * 128;
    const int n0 = blockIdx.y * 64;

    f32x4 acc[4][2];
#pragma unroll 4
    for (int mt = 0; mt < 4; ++mt)
#pragma unroll 2
        for (int nt = 0; nt < 2; ++nt)
            acc[mt][nt] = (f32x4){0.f, 0.f, 0.f, 0.f};

    for (int it = 0; it < Dn / 64; ++it) {
        const int kk0 = it * 64;
        __syncthreads();   // previous iteration's reads done
#pragma unroll 4
        for (int i = 0; i < 4; ++i) {
            int fl = i * 256 + tid;            // 1024 x 16B = 16 KB (X tile)
            int r = fl >> 3, c8 = fl & 7;
            __builtin_amdgcn_global_load_lds(
                (const __attribute__((address_space(1))) void*)
                    (Xg + (size_t)(m0 + r) * Dn + kk0 + c8 * 8),
                (__attribute__((address_space(3))) void*)&XsL[fl * 8],
                16, 0, 0);
        }
#pragma unroll 2
        for (int i = 0; i < 2; ++i) {
            int fl = i * 256 + tid;            // 512 x 16B = 8 KB (W tile)
            int r = fl >> 3, c8 = fl & 7;
            __builtin_amdgcn_global_load_lds(
                (const __attribute__((address_space(1))) void*)
                    (Wbf + (size_t)(n0 + r) * Dn + kk0 + c8 * 8),
                (__attribute__((address_space(3))) void*)&WsL[fl * 8],
                16, 0, 0);
        }
        __syncthreads();   // vmcnt(0) drain: tile resident

        __builtin_amdgcn_s_setprio(1);
#pragma unroll 2
        for (int ks = 0; ks < 2; ++ks) {
            bf16x8 af[4], bfr[2];
#pragma unroll 4
            for (int mt = 0; mt < 4; ++mt)
                af[mt] = *(const bf16x8*)&XsL[(mw + mt * 16 + l16) * 64 + ks * 32 + quad * 8];
#pragma unroll 2
            for (int nt = 0; nt < 2; ++nt)
                bfr[nt] = *(const bf16x8*)&WsL[(nw + nt * 16 + l16) * 64 + ks * 32 + quad * 8];
#pragma unroll 4
            for (int mt = 0; mt < 4; ++mt)
#pragma unroll 2
                for (int nt = 0; nt < 2; ++nt)
                    acc[mt][nt] = __builtin_amdgcn_mfma_f32_16x16x32_bf16(
                        af[mt], bfr[nt], acc[mt][nt], 0, 0, 0);
        }
        __builtin_amdgcn_s_setprio(0);
    }

#pragma unroll 2
    for (int nt = 0; nt < 2; ++nt) {
        int col = n0 + nw + nt * 16 + l16;
        float bb = bg[col];
#pragma unroll 4
        for (int mt = 0; mt < 4; ++mt)
#pragma unroll 4
            for (int r = 0; r < 4; ++r) {
                int row = m0 + mw + mt * 16 + quad * 4 + r;
                Yg[(size_t)row * Dn + col] = acc[mt][nt][r] + bb;
            }
    }
}

extern "C" void kernel_launch(void* const* d_in, const int* in_sizes, int n_in,
                              void* d_out, int out_size, void* d_ws, size_t ws_size,
                              hipStream_t stream) {
    const float* Q    = (const float*)d_in[0];
    const float* K    = (const float*)d_in[1];
    const float* V    = (const float*)d_in[2];
    const float* W    = (const float*)d_in[3];
    const float* bias = (const float*)d_in[4];

    unsigned short* Kbf = (unsigned short*)d_ws;                  // 8 MB
    unsigned short* Vt  = Kbf + (size_t)Bn * Ln * Dn;             // 8 MB
    unsigned short* Wbf = Vt  + (size_t)Bn * Ln * Dn;             // 2 MB
    unsigned short* X   = Wbf + (size_t)Dn * Dn;                  // 8 MB
    float* Y = (float*)d_out;

    dim3 gp(Ln / 64, Hn, Bn + 1);        // z=0..3: K/V prep; z=4: W prep
    prep_kernel<<<gp, 256, 0, stream>>>(K, V, W, Kbf, Vt, Wbf);

    attn_kernel<<<dim3(512, 1, 1), 256, 0, stream>>>(Q, Kbf, Vt, X);

    dim3 g2(Bn * Ln / 128, Dn / 64);     // 32 x 16 = 512 blocks, 2/CU
    proj_kernel<<<g2, 256, 0, stream>>>(X, Wbf, bias, Y);
}

// Round 8
// 147.456 us; speedup vs baseline: 1.2026x; 1.2026x over previous
//
#include <hip/hip_runtime.h>
#include <hip/hip_bf16.h>

typedef __attribute__((ext_vector_type(4))) float f32x4;
typedef __attribute__((ext_vector_type(8))) short bf16x8;

constexpr int Bn  = 4;
constexpr int Ln  = 1024;
constexpr int Dn  = 1024;
constexpr int Hn  = 16;
constexpr int HDn = 64;

static __device__ __forceinline__ unsigned short bf16r(float f) {
    union { float f; unsigned int u; } x;
    x.f = f;
    unsigned int r = x.u + 0x7fffu + ((x.u >> 16) & 1u);
    return (unsigned short)(r >> 16);
}

static __device__ __forceinline__ unsigned int pk2(float a, float b) {
    return (unsigned int)bf16r(a) | ((unsigned int)bf16r(b) << 16);
}

// ---------------------------------------------------------------------------
// Fused prep. grid (16,16,5) x 256 threads.  (unchanged)
// ---------------------------------------------------------------------------
__global__ __launch_bounds__(256) void prep_kernel(
    const float* __restrict__ Kg, const float* __restrict__ Vg,
    const float* __restrict__ Wg, unsigned short* __restrict__ Kbf,
    unsigned short* __restrict__ Vtg, unsigned short* __restrict__ Wbf)
{
    const int tid = threadIdx.x;
    if (blockIdx.z == 4) {
        const int r0 = blockIdx.x * 64, c0 = blockIdx.y * 64;
#pragma unroll 4
        for (int i = 0; i < 4; ++i) {
            int e4 = i * 256 + tid;
            int r = e4 >> 4, c4 = e4 & 15;
            const float* p = Wg + (size_t)(r0 + r) * Dn + c0 + c4 * 4;
            float4 v = *(const float4*)p;
            ushort4 o;
            o.x = bf16r(v.x); o.y = bf16r(v.y); o.z = bf16r(v.z); o.w = bf16r(v.w);
            *(ushort4*)(Wbf + (size_t)(r0 + r) * Dn + c0 + c4 * 4) = o;
        }
        return;
    }

    __shared__ unsigned short T[64][72];   // [d][k]
    const int k0 = blockIdx.x * 64;
    const int h  = blockIdx.y;
    const int b  = blockIdx.z;
    const float* Kb = Kg + (size_t)b * Ln * Dn + h * HDn;
    const float* Vb = Vg + (size_t)b * Ln * Dn + h * HDn;
    unsigned short* Ko = Kbf + (size_t)b * Ln * Dn + h * HDn;

#pragma unroll 4
    for (int i = 0; i < 4; ++i) {
        int e4 = i * 256 + tid;
        int r = e4 >> 4, c4 = e4 & 15;
        float4 kv = *(const float4*)(Kb + (size_t)(k0 + r) * Dn + c4 * 4);
        ushort4 o;
        o.x = bf16r(kv.x); o.y = bf16r(kv.y); o.z = bf16r(kv.z); o.w = bf16r(kv.w);
        *(ushort4*)(Ko + (size_t)(k0 + r) * Dn + c4 * 4) = o;
        float4 vv = *(const float4*)(Vb + (size_t)(k0 + r) * Dn + c4 * 4);
        T[c4 * 4 + 0][r] = bf16r(vv.x);
        T[c4 * 4 + 1][r] = bf16r(vv.y);
        T[c4 * 4 + 2][r] = bf16r(vv.z);
        T[c4 * 4 + 3][r] = bf16r(vv.w);
    }
    __syncthreads();
    unsigned short* out = Vtg + ((size_t)(b * Hn + h) * HDn) * Ln + k0;
#pragma unroll 2
    for (int i = 0; i < 2; ++i) {
        int e8 = i * 256 + tid;
        int r = e8 >> 3, c8 = e8 & 7;
        *(uint4*)(out + (size_t)r * Ln + c8 * 8) = *(const uint4*)&T[r][c8 * 8];
    }
}

// ---------------------------------------------------------------------------
// Flash attention, v7 = the proven 512-thread / q-tile-256 / grid-256 base
// (round-1: 33us) + single-barrier DOUBLE-BUFFERED K/V staging:
//   per tile: compute(buf[t&1]) -> write buf[(t+1)&1] -> one barrier.
// Barrier count halved; staging write overlaps other waves' compute.
// To fit 2x(K+V)+P in 64KB static LDS: no padding, XOR swizzle
// (16B-block col ^= row&7) -- bank-optimal for b128 reads (8 lanes/group =
// wave64 minimum) and b64 P-stores (4-way = minimum). Native uint4/uint2
// LDS arrays + bit_cast reads; forced unrolls (slow-toolchain insurance).
// ---------------------------------------------------------------------------
__global__ __launch_bounds__(512) void attn_kernel(
    const float* __restrict__ Qg, const unsigned short* __restrict__ Kbf,
    const unsigned short* __restrict__ Vtg, unsigned short* __restrict__ Xg)
{
    __shared__ uint4 Ks4[2][64][8];    // 16 KB  (dbuf, swizzled cols)
    __shared__ uint4 Vts4[2][64][8];   // 16 KB  [d][k]
    __shared__ uint2 Ps2[256][16];     // 32 KB  (swizzled, wave-private rows)

    const int tid  = threadIdx.x;
    const int wave = tid >> 6;     // 0..7
    const int lane = tid & 63;
    const int l16  = lane & 15;
    const int quad = lane >> 4;
    const int r7   = l16 & 7;      // swizzle key (rows used are l16 mod 16)
    const int wb   = wave * 32;

    // XCD-aware decode: flat = xcd + 8*(qt + 4*gg); bh = xcd + 8*gg.
    const int flat = blockIdx.x;
    const int xcd  = flat & 7;
    const int j    = flat >> 3;
    const int qt   = j & 3;
    const int gg   = j >> 2;
    const int g    = xcd + 8 * gg;   // 0..63
    const int h    = g & 15;
    const int b    = g >> 4;
    const int q0   = qt * 256;

    const uint4* Kb4  = (const uint4*)(Kbf + (size_t)b * Ln * Dn + h * HDn);
    const uint4* Vtb4 = (const uint4*)(Vtg + ((size_t)(b * Hn + h) * HDn) * Ln);

    // Q fragments (read exactly once). B-operand layout: n=l16, k=quad*8+j.
    bf16x8 bq[2][2];
#pragma unroll 2
    for (int hf = 0; hf < 2; ++hf) {
        const float* qp = Qg + ((size_t)b * Ln + q0 + wb + hf * 16 + l16) * Dn
                             + h * HDn + quad * 8;
        float4 a0 = *(const float4*)qp;
        float4 a1 = *(const float4*)(qp + 4);
        float4 a2 = *(const float4*)(qp + 32);
        float4 a3 = *(const float4*)(qp + 36);
        bq[hf][0][0] = (short)bf16r(a0.x); bq[hf][0][1] = (short)bf16r(a0.y);
        bq[hf][0][2] = (short)bf16r(a0.z); bq[hf][0][3] = (short)bf16r(a0.w);
        bq[hf][0][4] = (short)bf16r(a1.x); bq[hf][0][5] = (short)bf16r(a1.y);
        bq[hf][0][6] = (short)bf16r(a1.z); bq[hf][0][7] = (short)bf16r(a1.w);
        bq[hf][1][0] = (short)bf16r(a2.x); bq[hf][1][1] = (short)bf16r(a2.y);
        bq[hf][1][2] = (short)bf16r(a2.z); bq[hf][1][3] = (short)bf16r(a2.w);
        bq[hf][1][4] = (short)bf16r(a3.x); bq[hf][1][5] = (short)bf16r(a3.y);
        bq[hf][1][6] = (short)bf16r(a3.z); bq[hf][1][7] = (short)bf16r(a3.w);
    }

    const float SC = 1.4426950408889634f / 32.0f;   // log2(e)/sqrt(D)

    float lsum[2] = {0.f, 0.f};
    f32x4 Oacc[2][4];
#pragma unroll 2
    for (int hf = 0; hf < 2; ++hf)
#pragma unroll 4
        for (int d = 0; d < 4; ++d) Oacc[hf][d] = (f32x4){0.f, 0.f, 0.f, 0.f};

    // Staging: 512 threads, one uint4 of K and one of V per tile.
    const int sr = tid >> 3, sc = tid & 7;
    const int scs = sc ^ (sr & 7);           // swizzled column
    uint4 kreg, vreg;

    // Prologue: tile 0 -> buf 0; issue tile-1 loads; one barrier.
    kreg = Kb4[(size_t)sr * 128 + sc];
    vreg = Vtb4[(size_t)sr * 128 + sc];
    Ks4[0][sr][scs]  = kreg;                 // implicit vmcnt wait
    Vts4[0][sr][scs] = vreg;
    kreg = Kb4[(size_t)(64 + sr) * 128 + sc];
    vreg = Vtb4[(size_t)sr * 128 + 8 + sc];
    __syncthreads();

    constexpr int NT = Ln / 64;
    for (int it = 0; it < NT; ++it) {
        const int cur = it & 1;

        // S^T = K Q^T : A = K-frag (m=key), B = Q-frag (n=q). 8 reads, 16 MFMA.
        f32x4 st[2][4];
        __builtin_amdgcn_s_setprio(1);
#pragma unroll 4
        for (int n = 0; n < 4; ++n) {
            bf16x8 a0 = __builtin_bit_cast(bf16x8, Ks4[cur][n * 16 + l16][quad ^ r7]);
            bf16x8 a1 = __builtin_bit_cast(bf16x8, Ks4[cur][n * 16 + l16][(4 + quad) ^ r7]);
#pragma unroll 2
            for (int hf = 0; hf < 2; ++hf) {
                f32x4 acc = (f32x4){0.f, 0.f, 0.f, 0.f};
                acc = __builtin_amdgcn_mfma_f32_16x16x32_bf16(a0, bq[hf][0], acc, 0, 0, 0);
                acc = __builtin_amdgcn_mfma_f32_16x16x32_bf16(a1, bq[hf][1], acc, 0, 0, 0);
                st[hf][n] = acc;
            }
        }
        __builtin_amdgcn_s_setprio(0);

        // P = exp2(S^T * SC); packed b64 stores (swizzled); scalar row-sums.
#pragma unroll 2
        for (int hf = 0; hf < 2; ++hf) {
            float ls = 0.f;
#pragma unroll 4
            for (int n = 0; n < 4; ++n) {
                float p0 = __builtin_amdgcn_exp2f(st[hf][n][0] * SC);
                float p1 = __builtin_amdgcn_exp2f(st[hf][n][1] * SC);
                float p2 = __builtin_amdgcn_exp2f(st[hf][n][2] * SC);
                float p3 = __builtin_amdgcn_exp2f(st[hf][n][3] * SC);
                ls += (p0 + p1) + (p2 + p3);
                uint2 w;
                w.x = pk2(p0, p1);
                w.y = pk2(p2, p3);
                Ps2[wb + hf * 16 + l16][(n * 4 + quad) ^ (r7 << 1)] = w;
            }
            lsum[hf] += ls;
        }

        // O += P V. V B-frags shared across the two q-halves.
        __builtin_amdgcn_s_setprio(1);
#pragma unroll 2
        for (int kk = 0; kk < 2; ++kk) {
            bf16x8 bv[4];
#pragma unroll 4
            for (int dt = 0; dt < 4; ++dt)
                bv[dt] = __builtin_bit_cast(bf16x8,
                    Vts4[cur][dt * 16 + l16][(kk * 4 + quad) ^ r7]);
#pragma unroll 2
            for (int hf = 0; hf < 2; ++hf) {
                int blk = (kk * 4 + quad) ^ r7;
                bf16x8 ap = *(const bf16x8*)&Ps2[wb + hf * 16 + l16][blk * 2];
#pragma unroll 4
                for (int dt = 0; dt < 4; ++dt)
                    Oacc[hf][dt] = __builtin_amdgcn_mfma_f32_16x16x32_bf16(
                        ap, bv[dt], Oacc[hf][dt], 0, 0, 0);
            }
        }
        __builtin_amdgcn_s_setprio(0);

        // Stage tile it+1 into the other buffer (overlaps other waves'
        // compute); issue loads for tile it+2. ONE barrier per tile.
        if (it + 1 < NT) {
            Ks4[cur ^ 1][sr][scs]  = kreg;   // waits vmcnt for it+1 loads
            Vts4[cur ^ 1][sr][scs] = vreg;
            if (it + 2 < NT) {
                kreg = Kb4[(size_t)((it + 2) * 64 + sr) * 128 + sc];
                vreg = Vtb4[(size_t)sr * 128 + (it + 2) * 8 + sc];
            }
        }
        __syncthreads();
    }

    // Row sums live per-lane (q=l16); reduce across quads.
    float inv[2];
#pragma unroll 2
    for (int hf = 0; hf < 2; ++hf) {
        float rs = lsum[hf];
        rs += __shfl_xor(rs, 16, 64);
        rs += __shfl_xor(rs, 32, 64);
        inv[hf] = __builtin_amdgcn_rcpf(rs);
    }

    unsigned short* Xb = Xg + ((size_t)b * Ln + q0 + wb) * Dn + h * HDn;
#pragma unroll 2
    for (int hf = 0; hf < 2; ++hf)
#pragma unroll 4
        for (int r = 0; r < 4; ++r) {
            float iv = __shfl(inv[hf], quad * 4 + r, 64);
            int row = hf * 16 + quad * 4 + r;
#pragma unroll 4
            for (int dt = 0; dt < 4; ++dt)
                Xb[(size_t)row * Dn + dt * 16 + l16] = bf16r(Oacc[hf][dt][r] * iv);
        }
}

// ---------------------------------------------------------------------------
// Projection: Y = X @ W^T + b.  (unchanged from round 6)
// ---------------------------------------------------------------------------
__global__ __launch_bounds__(256) void proj_kernel(
    const unsigned short* __restrict__ Xg, const unsigned short* __restrict__ Wbf,
    const float* __restrict__ bg, float* __restrict__ Yg)
{
    __shared__ unsigned short XsL[128 * 64];   // 16 KB, linear (no pad!)
    __shared__ unsigned short WsL[64 * 64];    // 8 KB, linear

    const int tid  = threadIdx.x;
    const int wave = tid >> 6;
    const int lane = tid & 63;
    const int l16  = lane & 15;
    const int quad = lane >> 4;
    const int mw   = (wave & 1) * 64;
    const int nw   = (wave >> 1) * 32;

    const int m0 = blockIdx.x * 128;
    const int n0 = blockIdx.y * 64;

    f32x4 acc[4][2];
#pragma unroll 4
    for (int mt = 0; mt < 4; ++mt)
#pragma unroll 2
        for (int nt = 0; nt < 2; ++nt)
            acc[mt][nt] = (f32x4){0.f, 0.f, 0.f, 0.f};

    for (int it = 0; it < Dn / 64; ++it) {
        const int kk0 = it * 64;
        __syncthreads();   // previous iteration's reads done
#pragma unroll 4
        for (int i = 0; i < 4; ++i) {
            int fl = i * 256 + tid;            // 1024 x 16B = 16 KB (X tile)
            int r = fl >> 3, c8 = fl & 7;
            __builtin_amdgcn_global_load_lds(
                (const __attribute__((address_space(1))) void*)
                    (Xg + (size_t)(m0 + r) * Dn + kk0 + c8 * 8),
                (__attribute__((address_space(3))) void*)&XsL[fl * 8],
                16, 0, 0);
        }
#pragma unroll 2
        for (int i = 0; i < 2; ++i) {
            int fl = i * 256 + tid;            // 512 x 16B = 8 KB (W tile)
            int r = fl >> 3, c8 = fl & 7;
            __builtin_amdgcn_global_load_lds(
                (const __attribute__((address_space(1))) void*)
                    (Wbf + (size_t)(n0 + r) * Dn + kk0 + c8 * 8),
                (__attribute__((address_space(3))) void*)&WsL[fl * 8],
                16, 0, 0);
        }
        __syncthreads();   // vmcnt(0) drain: tile resident

        __builtin_amdgcn_s_setprio(1);
#pragma unroll 2
        for (int ks = 0; ks < 2; ++ks) {
            bf16x8 af[4], bfr[2];
#pragma unroll 4
            for (int mt = 0; mt < 4; ++mt)
                af[mt] = *(const bf16x8*)&XsL[(mw + mt * 16 + l16) * 64 + ks * 32 + quad * 8];
#pragma unroll 2
            for (int nt = 0; nt < 2; ++nt)
                bfr[nt] = *(const bf16x8*)&WsL[(nw + nt * 16 + l16) * 64 + ks * 32 + quad * 8];
#pragma unroll 4
            for (int mt = 0; mt < 4; ++mt)
#pragma unroll 2
                for (int nt = 0; nt < 2; ++nt)
                    acc[mt][nt] = __builtin_amdgcn_mfma_f32_16x16x32_bf16(
                        af[mt], bfr[nt], acc[mt][nt], 0, 0, 0);
        }
        __builtin_amdgcn_s_setprio(0);
    }

#pragma unroll 2
    for (int nt = 0; nt < 2; ++nt) {
        int col = n0 + nw + nt * 16 + l16;
        float bb = bg[col];
#pragma unroll 4
        for (int mt = 0; mt < 4; ++mt)
#pragma unroll 4
            for (int r = 0; r < 4; ++r) {
                int row = m0 + mw + mt * 16 + quad * 4 + r;
                Yg[(size_t)row * Dn + col] = acc[mt][nt][r] + bb;
            }
    }
}

extern "C" void kernel_launch(void* const* d_in, const int* in_sizes, int n_in,
                              void* d_out, int out_size, void* d_ws, size_t ws_size,
                              hipStream_t stream) {
    const float* Q    = (const float*)d_in[0];
    const float* K    = (const float*)d_in[1];
    const float* V    = (const float*)d_in[2];
    const float* W    = (const float*)d_in[3];
    const float* bias = (const float*)d_in[4];

    unsigned short* Kbf = (unsigned short*)d_ws;                  // 8 MB
    unsigned short* Vt  = Kbf + (size_t)Bn * Ln * Dn;             // 8 MB
    unsigned short* Wbf = Vt  + (size_t)Bn * Ln * Dn;             // 2 MB
    unsigned short* X   = Wbf + (size_t)Dn * Dn;                  // 8 MB
    float* Y = (float*)d_out;

    dim3 gp(Ln / 64, Hn, Bn + 1);        // z=0..3: K/V prep; z=4: W prep
    prep_kernel<<<gp, 256, 0, stream>>>(K, V, W, Kbf, Vt, Wbf);

    attn_kernel<<<dim3(256, 1, 1), 512, 0, stream>>>(Q, Kbf, Vt, X);

    dim3 g2(Bn * Ln / 128, Dn / 64);     // 32 x 16 = 512 blocks, 2/CU
    proj_kernel<<<g2, 256, 0, stream>>>(X, Wbf, bias, Y);
}

// Round 9
// 144.811 us; speedup vs baseline: 1.2246x; 1.0183x over previous
//
#include <hip/hip_runtime.h>
#include <hip/hip_bf16.h>

typedef __attribute__((ext_vector_type(4))) float f32x4;
typedef __attribute__((ext_vector_type(8))) short bf16x8;

constexpr int Bn  = 4;
constexpr int Ln  = 1024;
constexpr int Dn  = 1024;
constexpr int Hn  = 16;
constexpr int HDn = 64;

static __device__ __forceinline__ unsigned short bf16r(float f) {
    union { float f; unsigned int u; } x;
    x.f = f;
    unsigned int r = x.u + 0x7fffu + ((x.u >> 16) & 1u);
    return (unsigned short)(r >> 16);
}

static __device__ __forceinline__ unsigned int pk2(float a, float b) {
    return (unsigned int)bf16r(a) | ((unsigned int)bf16r(b) << 16);
}

// ---------------------------------------------------------------------------
// Fused prep. grid (16,16,5) x 256 threads.
//  z<4 : V f32 -> Vt bf16 [B,H,hd,L] (per-head transpose via LDS). K pass
//        REMOVED (attn converts K inline from f32 -> no 24MB round-trip).
//  z==4: W f32 -> Wbf bf16, 64x64 tile.
// ---------------------------------------------------------------------------
__global__ __launch_bounds__(256) void prep_kernel(
    const float* __restrict__ Vg, const float* __restrict__ Wg,
    unsigned short* __restrict__ Vtg, unsigned short* __restrict__ Wbf)
{
    const int tid = threadIdx.x;
    if (blockIdx.z == 4) {
        const int r0 = blockIdx.x * 64, c0 = blockIdx.y * 64;
#pragma unroll 4
        for (int i = 0; i < 4; ++i) {
            int e4 = i * 256 + tid;
            int r = e4 >> 4, c4 = e4 & 15;
            const float* p = Wg + (size_t)(r0 + r) * Dn + c0 + c4 * 4;
            float4 v = *(const float4*)p;
            ushort4 o;
            o.x = bf16r(v.x); o.y = bf16r(v.y); o.z = bf16r(v.z); o.w = bf16r(v.w);
            *(ushort4*)(Wbf + (size_t)(r0 + r) * Dn + c0 + c4 * 4) = o;
        }
        return;
    }

    __shared__ unsigned short T[64][72];   // [d][k]
    const int k0 = blockIdx.x * 64;
    const int h  = blockIdx.y;
    const int b  = blockIdx.z;
    const float* Vb = Vg + (size_t)b * Ln * Dn + h * HDn;

#pragma unroll 4
    for (int i = 0; i < 4; ++i) {
        int e4 = i * 256 + tid;
        int r = e4 >> 4, c4 = e4 & 15;
        float4 vv = *(const float4*)(Vb + (size_t)(k0 + r) * Dn + c4 * 4);
        T[c4 * 4 + 0][r] = bf16r(vv.x);
        T[c4 * 4 + 1][r] = bf16r(vv.y);
        T[c4 * 4 + 2][r] = bf16r(vv.z);
        T[c4 * 4 + 3][r] = bf16r(vv.w);
    }
    __syncthreads();
    unsigned short* out = Vtg + ((size_t)(b * Hn + h) * HDn) * Ln + k0;
#pragma unroll 2
    for (int i = 0; i < 2; ++i) {
        int e8 = i * 256 + tid;
        int r = e8 >> 3, c8 = e8 & 7;
        *(uint4*)(out + (size_t)r * Ln + c8 * 8) = *(const uint4*)&T[r][c8 * 8];
    }
}

// ---------------------------------------------------------------------------
// Flash attention, v8 = v7 (512 thr, q-tile 256, grid 256, single-barrier
// double-buffered K/V, XOR-swizzled LDS, builtin exp2, forced unrolls)
// + INLINE K conversion: K staged directly from f32 (2 float4 raw regs,
// pk2-packed at the LDS-write point so the vmcnt wait stays deferred).
// Removes the prep K pass (24MB HBM round-trip). K f32 re-reads by the 4
// q-tile blocks of a (b,h) are XCD-local L2 hits (2MB < 4MB L2).
// ---------------------------------------------------------------------------
__global__ __launch_bounds__(512) void attn_kernel(
    const float* __restrict__ Qg, const float* __restrict__ Kg,
    const unsigned short* __restrict__ Vtg, unsigned short* __restrict__ Xg)
{
    __shared__ uint4 Ks4[2][64][8];    // 16 KB  (dbuf, swizzled cols)
    __shared__ uint4 Vts4[2][64][8];   // 16 KB  [d][k]
    __shared__ uint2 Ps2[256][16];     // 32 KB  (swizzled, wave-private rows)

    const int tid  = threadIdx.x;
    const int wave = tid >> 6;     // 0..7
    const int lane = tid & 63;
    const int l16  = lane & 15;
    const int quad = lane >> 4;
    const int r7   = l16 & 7;      // swizzle key
    const int wb   = wave * 32;

    // XCD-aware decode: flat = xcd + 8*(qt + 4*gg); bh = xcd + 8*gg.
    const int flat = blockIdx.x;
    const int xcd  = flat & 7;
    const int j    = flat >> 3;
    const int qt   = j & 3;
    const int gg   = j >> 2;
    const int g    = xcd + 8 * gg;   // 0..63
    const int h    = g & 15;
    const int b    = g >> 4;
    const int q0   = qt * 256;

    const float* Kf   = Kg + (size_t)b * Ln * Dn + h * HDn;          // f32
    const uint4* Vtb4 = (const uint4*)(Vtg + ((size_t)(b * Hn + h) * HDn) * Ln);

    // Q fragments (read exactly once). B-operand layout: n=l16, k=quad*8+j.
    bf16x8 bq[2][2];
#pragma unroll 2
    for (int hf = 0; hf < 2; ++hf) {
        const float* qp = Qg + ((size_t)b * Ln + q0 + wb + hf * 16 + l16) * Dn
                             + h * HDn + quad * 8;
        float4 a0 = *(const float4*)qp;
        float4 a1 = *(const float4*)(qp + 4);
        float4 a2 = *(const float4*)(qp + 32);
        float4 a3 = *(const float4*)(qp + 36);
        bq[hf][0][0] = (short)bf16r(a0.x); bq[hf][0][1] = (short)bf16r(a0.y);
        bq[hf][0][2] = (short)bf16r(a0.z); bq[hf][0][3] = (short)bf16r(a0.w);
        bq[hf][0][4] = (short)bf16r(a1.x); bq[hf][0][5] = (short)bf16r(a1.y);
        bq[hf][0][6] = (short)bf16r(a1.z); bq[hf][0][7] = (short)bf16r(a1.w);
        bq[hf][1][0] = (short)bf16r(a2.x); bq[hf][1][1] = (short)bf16r(a2.y);
        bq[hf][1][2] = (short)bf16r(a2.z); bq[hf][1][3] = (short)bf16r(a2.w);
        bq[hf][1][4] = (short)bf16r(a3.x); bq[hf][1][5] = (short)bf16r(a3.y);
        bq[hf][1][6] = (short)bf16r(a3.z); bq[hf][1][7] = (short)bf16r(a3.w);
    }

    const float SC = 1.4426950408889634f / 32.0f;   // log2(e)/sqrt(D)

    float lsum[2] = {0.f, 0.f};
    f32x4 Oacc[2][4];
#pragma unroll 2
    for (int hf = 0; hf < 2; ++hf)
#pragma unroll 4
        for (int d = 0; d < 4; ++d) Oacc[hf][d] = (f32x4){0.f, 0.f, 0.f, 0.f};

    // Staging: 512 threads; K = 2 raw float4 (converted at write), V = uint4.
    const int sr = tid >> 3, sc = tid & 7;
    const int scs = sc ^ (sr & 7);           // swizzled column
    float4 kr0, kr1;
    uint4 vreg;

    // Prologue: tile 0 -> buf 0; issue tile-1 loads; one barrier.
    kr0 = *(const float4*)(Kf + (size_t)sr * Dn + sc * 8);
    kr1 = *(const float4*)(Kf + (size_t)sr * Dn + sc * 8 + 4);
    vreg = Vtb4[(size_t)sr * 128 + sc];
    Ks4[0][sr][scs] = (uint4){pk2(kr0.x, kr0.y), pk2(kr0.z, kr0.w),
                              pk2(kr1.x, kr1.y), pk2(kr1.z, kr1.w)};
    Vts4[0][sr][scs] = vreg;
    kr0 = *(const float4*)(Kf + (size_t)(64 + sr) * Dn + sc * 8);
    kr1 = *(const float4*)(Kf + (size_t)(64 + sr) * Dn + sc * 8 + 4);
    vreg = Vtb4[(size_t)sr * 128 + 8 + sc];
    __syncthreads();

    constexpr int NT = Ln / 64;
    for (int it = 0; it < NT; ++it) {
        const int cur = it & 1;

        // S^T = K Q^T : A = K-frag (m=key), B = Q-frag (n=q). 8 reads, 16 MFMA.
        f32x4 st[2][4];
        __builtin_amdgcn_s_setprio(1);
#pragma unroll 4
        for (int n = 0; n < 4; ++n) {
            bf16x8 a0 = __builtin_bit_cast(bf16x8, Ks4[cur][n * 16 + l16][quad ^ r7]);
            bf16x8 a1 = __builtin_bit_cast(bf16x8, Ks4[cur][n * 16 + l16][(4 + quad) ^ r7]);
#pragma unroll 2
            for (int hf = 0; hf < 2; ++hf) {
                f32x4 acc = (f32x4){0.f, 0.f, 0.f, 0.f};
                acc = __builtin_amdgcn_mfma_f32_16x16x32_bf16(a0, bq[hf][0], acc, 0, 0, 0);
                acc = __builtin_amdgcn_mfma_f32_16x16x32_bf16(a1, bq[hf][1], acc, 0, 0, 0);
                st[hf][n] = acc;
            }
        }
        __builtin_amdgcn_s_setprio(0);

        // P = exp2(S^T * SC); packed b64 stores (swizzled); scalar row-sums.
#pragma unroll 2
        for (int hf = 0; hf < 2; ++hf) {
            float ls = 0.f;
#pragma unroll 4
            for (int n = 0; n < 4; ++n) {
                float p0 = __builtin_amdgcn_exp2f(st[hf][n][0] * SC);
                float p1 = __builtin_amdgcn_exp2f(st[hf][n][1] * SC);
                float p2 = __builtin_amdgcn_exp2f(st[hf][n][2] * SC);
                float p3 = __builtin_amdgcn_exp2f(st[hf][n][3] * SC);
                ls += (p0 + p1) + (p2 + p3);
                uint2 w;
                w.x = pk2(p0, p1);
                w.y = pk2(p2, p3);
                Ps2[wb + hf * 16 + l16][(n * 4 + quad) ^ (r7 << 1)] = w;
            }
            lsum[hf] += ls;
        }

        // O += P V. V B-frags shared across the two q-halves.
        __builtin_amdgcn_s_setprio(1);
#pragma unroll 2
        for (int kk = 0; kk < 2; ++kk) {
            bf16x8 bv[4];
#pragma unroll 4
            for (int dt = 0; dt < 4; ++dt)
                bv[dt] = __builtin_bit_cast(bf16x8,
                    Vts4[cur][dt * 16 + l16][(kk * 4 + quad) ^ r7]);
#pragma unroll 2
            for (int hf = 0; hf < 2; ++hf) {
                int blk = (kk * 4 + quad) ^ r7;
                bf16x8 ap = *(const bf16x8*)&Ps2[wb + hf * 16 + l16][blk * 2];
#pragma unroll 4
                for (int dt = 0; dt < 4; ++dt)
                    Oacc[hf][dt] = __builtin_amdgcn_mfma_f32_16x16x32_bf16(
                        ap, bv[dt], Oacc[hf][dt], 0, 0, 0);
            }
        }
        __builtin_amdgcn_s_setprio(0);

        // Stage tile it+1 into the other buffer (overlaps other waves'
        // compute); issue loads for tile it+2. ONE barrier per tile.
        if (it + 1 < NT) {
            Ks4[cur ^ 1][sr][scs] = (uint4){pk2(kr0.x, kr0.y), pk2(kr0.z, kr0.w),
                                            pk2(kr1.x, kr1.y), pk2(kr1.z, kr1.w)};
            Vts4[cur ^ 1][sr][scs] = vreg;
            if (it + 2 < NT) {
                kr0 = *(const float4*)(Kf + (size_t)((it + 2) * 64 + sr) * Dn + sc * 8);
                kr1 = *(const float4*)(Kf + (size_t)((it + 2) * 64 + sr) * Dn + sc * 8 + 4);
                vreg = Vtb4[(size_t)sr * 128 + (it + 2) * 8 + sc];
            }
        }
        __syncthreads();
    }

    // Row sums live per-lane (q=l16); reduce across quads.
    float inv[2];
#pragma unroll 2
    for (int hf = 0; hf < 2; ++hf) {
        float rs = lsum[hf];
        rs += __shfl_xor(rs, 16, 64);
        rs += __shfl_xor(rs, 32, 64);
        inv[hf] = __builtin_amdgcn_rcpf(rs);
    }

    unsigned short* Xb = Xg + ((size_t)b * Ln + q0 + wb) * Dn + h * HDn;
#pragma unroll 2
    for (int hf = 0; hf < 2; ++hf)
#pragma unroll 4
        for (int r = 0; r < 4; ++r) {
            float iv = __shfl(inv[hf], quad * 4 + r, 64);
            int row = hf * 16 + quad * 4 + r;
#pragma unroll 4
            for (int dt = 0; dt < 4; ++dt)
                Xb[(size_t)row * Dn + dt * 16 + l16] = bf16r(Oacc[hf][dt][r] * iv);
        }
}

// ---------------------------------------------------------------------------
// Projection: Y = X @ W^T + b.  (unchanged)
// ---------------------------------------------------------------------------
__global__ __launch_bounds__(256) void proj_kernel(
    const unsigned short* __restrict__ Xg, const unsigned short* __restrict__ Wbf,
    const float* __restrict__ bg, float* __restrict__ Yg)
{
    __shared__ unsigned short XsL[128 * 64];   // 16 KB, linear (no pad!)
    __shared__ unsigned short WsL[64 * 64];    // 8 KB, linear

    const int tid  = threadIdx.x;
    const int wave = tid >> 6;
    const int lane = tid & 63;
    const int l16  = lane & 15;
    const int quad = lane >> 4;
    const int mw   = (wave & 1) * 64;
    const int nw   = (wave >> 1) * 32;

    const int m0 = blockIdx.x * 128;
    const int n0 = blockIdx.y * 64;

    f32x4 acc[4][2];
#pragma unroll 4
    for (int mt = 0; mt < 4; ++mt)
#pragma unroll 2
        for (int nt = 0; nt < 2; ++nt)
            acc[mt][nt] = (f32x4){0.f, 0.f, 0.f, 0.f};

    for (int it = 0; it < Dn / 64; ++it) {
        const int kk0 = it * 64;
        __syncthreads();   // previous iteration's reads done
#pragma unroll 4
        for (int i = 0; i < 4; ++i) {
            int fl = i * 256 + tid;            // 1024 x 16B = 16 KB (X tile)
            int r = fl >> 3, c8 = fl & 7;
            __builtin_amdgcn_global_load_lds(
                (const __attribute__((address_space(1))) void*)
                    (Xg + (size_t)(m0 + r) * Dn + kk0 + c8 * 8),
                (__attribute__((address_space(3))) void*)&XsL[fl * 8],
                16, 0, 0);
        }
#pragma unroll 2
        for (int i = 0; i < 2; ++i) {
            int fl = i * 256 + tid;            // 512 x 16B = 8 KB (W tile)
            int r = fl >> 3, c8 = fl & 7;
            __builtin_amdgcn_global_load_lds(
                (const __attribute__((address_space(1))) void*)
                    (Wbf + (size_t)(n0 + r) * Dn + kk0 + c8 * 8),
                (__attribute__((address_space(3))) void*)&WsL[fl * 8],
                16, 0, 0);
        }
        __syncthreads();   // vmcnt(0) drain: tile resident

        __builtin_amdgcn_s_setprio(1);
#pragma unroll 2
        for (int ks = 0; ks < 2; ++ks) {
            bf16x8 af[4], bfr[2];
#pragma unroll 4
            for (int mt = 0; mt < 4; ++mt)
                af[mt] = *(const bf16x8*)&XsL[(mw + mt * 16 + l16) * 64 + ks * 32 + quad * 8];
#pragma unroll 2
            for (int nt = 0; nt < 2; ++nt)
                bfr[nt] = *(const bf16x8*)&WsL[(nw + nt * 16 + l16) * 64 + ks * 32 + quad * 8];
#pragma unroll 4
            for (int mt = 0; mt < 4; ++mt)
#pragma unroll 2
                for (int nt = 0; nt < 2; ++nt)
                    acc[mt][nt] = __builtin_amdgcn_mfma_f32_16x16x32_bf16(
                        af[mt], bfr[nt], acc[mt][nt], 0, 0, 0);
        }
        __builtin_amdgcn_s_setprio(0);
    }

#pragma unroll 2
    for (int nt = 0; nt < 2; ++nt) {
        int col = n0 + nw + nt * 16 + l16;
        float bb = bg[col];
#pragma unroll 4
        for (int mt = 0; mt < 4; ++mt)
#pragma unroll 4
            for (int r = 0; r < 4; ++r) {
                int row = m0 + mw + mt * 16 + quad * 4 + r;
                Yg[(size_t)row * Dn + col] = acc[mt][nt][r] + bb;
            }
    }
}

extern "C" void kernel_launch(void* const* d_in, const int* in_sizes, int n_in,
                              void* d_out, int out_size, void* d_ws, size_t ws_size,
                              hipStream_t stream) {
    const float* Q    = (const float*)d_in[0];
    const float* K    = (const float*)d_in[1];
    const float* V    = (const float*)d_in[2];
    const float* W    = (const float*)d_in[3];
    const float* bias = (const float*)d_in[4];

    unsigned short* Vt  = (unsigned short*)d_ws;                  // 8 MB
    unsigned short* Wbf = Vt + (size_t)Bn * Ln * Dn;              // 2 MB
    unsigned short* X   = Wbf + (size_t)Dn * Dn;                  // 8 MB
    float* Y = (float*)d_out;

    dim3 gp(Ln / 64, Hn, Bn + 1);        // z=0..3: V prep; z=4: W prep
    prep_kernel<<<gp, 256, 0, stream>>>(V, W, Vt, Wbf);

    attn_kernel<<<dim3(256, 1, 1), 512, 0, stream>>>(Q, K, Vt, X);

    dim3 g2(Bn * Ln / 128, Dn / 64);     // 32 x 16 = 512 blocks, 2/CU
    proj_kernel<<<g2, 256, 0, stream>>>(X, Wbf, bias, Y);
}